// Round 1
// 4094.363 us; speedup vs baseline: 2.3159x; 2.3159x over previous
//
#include <hip/hip_runtime.h>
#include <stdint.h>
#include <math.h>

// Persistent bidirectional-LSTM encoder for MI355X (gfx950).
// B=64, T=512, D_IN=512, H=1024. ALL I/O IS FLOAT32 (per the reference);
// MFMA compute in bf16 (round-nearest inputs), f32 accumulate, f32 output.
//
// Partition: 256 WGs x 512 threads. wg = [group(2) | dir(2) | seg(64)]
//   group: batch rows 32g..32g+31; dir: fwd/bwd scan; seg: 16 hidden units.
// K split UNIFORM across 8 waves: each wave owns 64 x-cols + 128 h-cols.
// Per step each WG computes a M32 x N64 x K1536 tile, LDS reduce, cell
// update. Cross-WG h/flags via relaxed agent-scope atomics (sc1 loads and
// stores at the coherence point; immune to per-XCD L2 staleness).
//
// Sync redesign vs previous version (the 18.4us/step critical path):
//  - byte flags, one 64B line per domain, domains padded 256B apart
//  - ONLY wave 0 polls (8x poll-traffic cut), others released by barrier
//  - flag store is RELAXED, not RELEASE (h stores are sc1 and already
//    vmcnt-drained by the preceding __syncthreads; agent-release would
//    L2-writeback every step on the critical path for nothing)
//  - out[] HBM store moved AFTER the flag publish (its drain no longer
//    sits inside the pre-flag barrier)

#define TSEQ 512
#define DIN  512

typedef short  short8  __attribute__((ext_vector_type(8)));
typedef float  float4_ __attribute__((ext_vector_type(4)));
typedef float  float8_ __attribute__((ext_vector_type(8)));

__device__ __forceinline__ unsigned short f2bf(float f) {
  union { float f; unsigned int i; } v; v.f = f;
  unsigned int r = (v.i + 0x7FFFu + ((v.i >> 16) & 1u)) >> 16;
  return (unsigned short)r;
}
// 8 consecutive f32 -> bf16x8 fragment (round-nearest-even)
__device__ __forceinline__ short8 cvt8(const float* p) {
  float8_ f = *reinterpret_cast<const float8_*>(p);
  short8 s;
  #pragma unroll
  for (int i = 0; i < 8; ++i) s[i] = (short)f2bf(f[i]);
  return s;
}
// 16B (8 bf16) read through the coherence point: 2 x 8B relaxed agent atomics.
__device__ __forceinline__ short8 ald16(const unsigned long long* b64, size_t elem) {
  union { unsigned long long u[2]; short8 s; } v;
  const unsigned long long* p = b64 + (elem >> 2);
  v.u[0] = __hip_atomic_load(p,     __ATOMIC_RELAXED, __HIP_MEMORY_SCOPE_AGENT);
  v.u[1] = __hip_atomic_load(p + 1, __ATOMIC_RELAXED, __HIP_MEMORY_SCOPE_AGENT);
  return v.s;
}
__device__ __forceinline__ float sigf(float x) {
  x = fminf(fmaxf(x, -30.f), 30.f);
  return 1.f / (1.f + expf(-x));
}

__global__ __launch_bounds__(512, 2)
void lstm_encoder_kernel(
    const float* __restrict__ x,
    const float* __restrict__ Wih_f, const float* __restrict__ Whh_f,
    const float* __restrict__ bih_f, const float* __restrict__ bhh_f,
    const float* __restrict__ Wih_b, const float* __restrict__ Whh_b,
    const float* __restrict__ bih_b, const float* __restrict__ bhh_b,
    const float* __restrict__ fcW, const float* __restrict__ fcb,
    const float* __restrict__ fhW, const float* __restrict__ fhb,
    float* __restrict__ out,
    unsigned char* __restrict__ flags, int* __restrict__ done,
    unsigned short* __restrict__ hbuf_f, unsigned short* __restrict__ hbuf_b,
    unsigned short* __restrict__ cend)
{
  __shared__ float part[8][4][32][18];   // [wave][gate][Mrow][unit(+pad)]

  const int tid  = threadIdx.x;
  const int wv   = tid >> 6;
  const int lane = tid & 63;
  const int quad = lane >> 4;
  const int u16  = lane & 15;

  const int wg    = blockIdx.x;
  const int group = wg >> 7;
  const int rem   = wg & 127;
  const int dir   = rem >> 6;
  const int seg   = rem & 63;
  const int j0    = seg * 16;
  const int dom   = group * 2 + dir;
  unsigned char* myflags = flags + dom * 256;   // 64 byte-flags = ONE 64B line

  const float* Wih = dir ? Wih_b : Wih_f;
  const float* Whh = dir ? Whh_b : Whh_f;
  const float* bih = dir ? bih_b : bih_f;
  const float* bhh = dir ? bhh_b : bhh_f;
  unsigned short* hbuf = dir ? hbuf_b : hbuf_f;
  const unsigned long long* hbuf64 = (const unsigned long long*)hbuf;
  unsigned int* hbuf32 = (unsigned int*)hbuf;

  // uniform K split: wave wv owns x-cols [wv*64, wv*64+64) (chunks 0-1)
  // and h-cols [wv*128, wv*128+128) (chunks 2-5)
  const int wx = wv * 64;
  const int wh = wv * 128;

  // stationary bf16 weight fragments: B[k][n=lane&15], 8 contiguous k/lane
  short8 Bf[6][4];
  #pragma unroll
  for (int kc = 0; kc < 6; ++kc) {
    #pragma unroll
    for (int nt = 0; nt < 4; ++nt) {
      const int row = nt * 1024 + j0 + u16;          // gate nt, unit j0+u16
      const float* p = (kc < 2)
          ? (Wih + (size_t)row * 512  + (wx + kc * 32 + quad * 8))
          : (Whh + (size_t)row * 1024 + (wh + (kc - 2) * 32 + quad * 8));
      Bf[kc][nt] = cvt8(p);
    }
  }
  float bias[4];
  #pragma unroll
  for (int g = 0; g < 4; ++g)
    bias[g] = bih[g * 1024 + j0 + u16] + bhh[g * 1024 + j0 + u16];

  float4_ acc[2][4];
  #pragma unroll
  for (int mt = 0; mt < 2; ++mt)
    #pragma unroll
    for (int nt = 0; nt < 4; ++nt) acc[mt][nt] = (float4_){0.f, 0.f, 0.f, 0.f};

  float cstate = 0.f;
  const int arow0 = group * 32 + u16;

  auto gemm_x = [&](int t) {
    const int tx = dir ? (TSEQ - 1 - t) : t;
    #pragma unroll
    for (int kc = 0; kc < 2; ++kc) {
      const int klane = wx + kc * 32 + quad * 8;
      const float* base = x + ((size_t)arow0 * TSEQ + tx) * DIN + klane;
      short8 a0 = cvt8(base);
      short8 a1 = cvt8(base + (size_t)16 * TSEQ * DIN);
      #pragma unroll
      for (int nt = 0; nt < 4; ++nt) {
        acc[0][nt] = __builtin_amdgcn_mfma_f32_16x16x32_bf16(a0, Bf[kc][nt], acc[0][nt], 0, 0, 0);
        acc[1][nt] = __builtin_amdgcn_mfma_f32_16x16x32_bf16(a1, Bf[kc][nt], acc[1][nt], 0, 0, 0);
      }
    }
  };
  auto gemm_h = [&](int t) {
    const int rp = (t + 1) & 1;                 // parity holding h(t-1)
    #pragma unroll
    for (int kc = 2; kc < 6; ++kc) {
      const int kh = wh + (kc - 2) * 32 + quad * 8;
      const size_t eb = (size_t)(rp * 64 + arow0) * 1024 + kh;
      short8 a0 = ald16(hbuf64, eb);
      short8 a1 = ald16(hbuf64, eb + (size_t)16 * 1024);
      #pragma unroll
      for (int nt = 0; nt < 4; ++nt) {
        acc[0][nt] = __builtin_amdgcn_mfma_f32_16x16x32_bf16(a0, Bf[kc][nt], acc[0][nt], 0, 0, 0);
        acc[1][nt] = __builtin_amdgcn_mfma_f32_16x16x32_bf16(a1, Bf[kc][nt], acc[1][nt], 0, 0, 0);
      }
    }
  };

  gemm_x(0);                                    // x-part of step 0 (all waves)

  const int row_l = wv * 4 + quad;
  const int bglob = group * 32 + row_l;

  for (int t = 0; t < TSEQ; ++t) {
    // wave 0 polls all 64 producer byte-flags (one 64B line); skew <= 1 step
    // so the 8-bit wrapped compare ((v - t) & 0xFF) <= 1 is exact.
    if (wv == 0) {
      const unsigned char tb = (unsigned char)t;
      int it = 0;
      for (;;) {
        unsigned char v = __hip_atomic_load(myflags + lane, __ATOMIC_RELAXED, __HIP_MEMORY_SCOPE_AGENT);
        if (__ballot((unsigned char)(v - tb) > 1u) == 0ull) break;
        if (++it > 300000) break;               // bounded: never hard-hang
        __builtin_amdgcn_s_sleep(2);
      }
    }
    __syncthreads();                            // release waves 1..7
    __builtin_amdgcn_fence(__ATOMIC_ACQUIRE, "workgroup");
    __builtin_amdgcn_sched_barrier(0);

    gemm_h(t);                                  // recurrent part (sc1 h reads)

    #pragma unroll
    for (int mt = 0; mt < 2; ++mt)
      #pragma unroll
      for (int nt = 0; nt < 4; ++nt)
        #pragma unroll
        for (int r = 0; r < 4; ++r)
          part[wv][nt][mt * 16 + quad * 4 + r][u16] = acc[mt][nt][r];
    __syncthreads();

    float gts[4];
    #pragma unroll
    for (int g = 0; g < 4; ++g) {
      float s = bias[g];
      #pragma unroll
      for (int p = 0; p < 8; ++p) s += part[p][g][row_l][u16];
      gts[g] = s;
    }
    float iv = sigf(gts[0]);
    float fv = sigf(gts[1]);
    float gv = tanhf(gts[2]);
    float ov = sigf(gts[3]);
    cstate = fv * cstate + iv * gv;
    float hv = ov * tanhf(cstate);
    unsigned short h16 = f2bf(hv);

    // publish h(t) for consumers: packed bf16 pairs via coherence point
    {
      unsigned int h32 = h16;
      unsigned int oth = __shfl_xor(h32, 1);
      if ((u16 & 1) == 0) {
        unsigned int val = h32 | (oth << 16);
        size_t elem = (size_t)((t & 1) * 64 + bglob) * 1024 + j0 + u16;
        __hip_atomic_store(hbuf32 + (elem >> 1), val, __ATOMIC_RELAXED, __HIP_MEMORY_SCOPE_AGENT);
      }
    }
    __syncthreads();   // per-wave vmcnt drain: all h stores are at L3 now

    // RELAXED flag store: h stores above are sc1 and drained; L3 serializes
    // flag-after-data. No agent-release (no per-step L2 writeback).
    if (tid == 0)
      __hip_atomic_store(myflags + seg, (unsigned char)(t + 1), __ATOMIC_RELAXED, __HIP_MEMORY_SCOPE_AGENT);

    #pragma unroll
    for (int mt = 0; mt < 2; ++mt)
      #pragma unroll
      for (int nt = 0; nt < 4; ++nt) acc[mt][nt] = (float4_){0.f, 0.f, 0.f, 0.f};
    if (t + 1 < TSEQ) gemm_x(t + 1);            // x-part of t+1 in poll shadow

    // hidden_states[b][t][dir*1024+j] in FULL f32 — AFTER the flag publish,
    // so its HBM drain is off the inter-WG critical path.
    out[((size_t)bglob * TSEQ + t) * 2048 + dir * 1024 + j0 + u16] = hv;
  }

  // publish final cell state (bf16, coherence-point)
  {
    unsigned short c16 = f2bf(cstate);
    unsigned int c32 = c16;
    unsigned int oth = __shfl_xor(c32, 1);
    if ((u16 & 1) == 0) {
      size_t elem = (size_t)bglob * 2048 + dir * 1024 + j0 + u16;
      __hip_atomic_store((unsigned int*)cend + (elem >> 1), c32 | (oth << 16),
                         __ATOMIC_RELAXED, __HIP_MEMORY_SCOPE_AGENT);
    }
  }
  __syncthreads();                              // drain cend + out stores
  if (tid == 0)
    __hip_atomic_store(done + wg, 1, __ATOMIC_RELAXED, __HIP_MEMORY_SCOPE_AGENT);
  if (wg >= 128) return;                        // only epilogue WGs wait

  {
    int it = 0;
    for (;;) {
      int ok = 1;
      #pragma unroll
      for (int j = 0; j < 4; ++j) {
        int v = __hip_atomic_load(done + lane * 4 + j, __ATOMIC_RELAXED, __HIP_MEMORY_SCOPE_AGENT);
        ok &= (v != 0);
      }
      if (__ballot(!ok) == 0ull) break;
      if (++it > 300000) break;
      __builtin_amdgcn_s_sleep(4);
    }
    __builtin_amdgcn_fence(__ATOMIC_ACQUIRE, "workgroup");
    __builtin_amdgcn_sched_barrier(0);
  }
  if (wv >= 4) return;

  // epilogue: initial_hiddens = tanh(h_end @ fh_W^T + fh_b)   (mat 0)
  //           initial_cells   = tanh(c_end @ fc_W^T + fc_b)   (mat 1)
  const int mat   = wg >> 6;
  const int nbase = (wg & 63) * 16;
  const float* Wp = mat ? fcW : fhW;
  const float* bp = mat ? fcb : fhb;
  const int m0 = wv * 16;
  const int am = m0 + u16;
  const unsigned long long* hf64 = (const unsigned long long*)hbuf_f;
  const unsigned long long* hb64 = (const unsigned long long*)hbuf_b;
  const unsigned long long* ce64 = (const unsigned long long*)cend;
  float4_ a4 = (float4_){0.f, 0.f, 0.f, 0.f};
  #pragma unroll 4
  for (int kc = 0; kc < 64; ++kc) {
    const int k = kc * 32 + quad * 8;
    short8 av, bv;
    if (mat == 0) {                          // h(T-1) lives at parity 1
      av = (kc < 32) ? ald16(hf64, (size_t)(64 + am) * 1024 + k)
                     : ald16(hb64, (size_t)(64 + am) * 1024 + (k - 1024));
    } else {
      av = ald16(ce64, (size_t)am * 2048 + k);
    }
    bv = cvt8(Wp + (size_t)(nbase + u16) * 2048 + k);
    a4 = __builtin_amdgcn_mfma_f32_16x16x32_bf16(av, bv, a4, 0, 0, 0);
  }
  float bb = bp[nbase + u16];
  #pragma unroll
  for (int r = 0; r < 4; ++r) {
    const int row = m0 + quad * 4 + r;
    float v = tanhf(a4[r] + bb);
    out[(size_t)67108864 + (size_t)mat * 65536 + (size_t)row * 1024 + nbase + u16] = v;
  }
}

extern "C" void kernel_launch(void* const* d_in, const int* in_sizes, int n_in,
                              void* d_out, int out_size, void* d_ws, size_t ws_size,
                              hipStream_t stream) {
  char* ws = (char*)d_ws;
  // ws map: [0,1KB) byte-flags (4 domains x 256B pad, 64 used each),
  //         [4KB,5KB) done (256 ints),
  //         [8KB,+256KB) h_f double buffer, +256KB h_b, +256KB c_end (bf16)
  unsigned char* flags = (unsigned char*)(ws);
  int* done  = (int*)(ws + 4096);
  unsigned short* hf = (unsigned short*)(ws + 8192);
  unsigned short* hb = (unsigned short*)(ws + 8192 + 262144);
  unsigned short* ce = (unsigned short*)(ws + 8192 + 524288);
  hipMemsetAsync(d_ws, 0, 8192 + 524288, stream);   // zero flags + h(-1)=0
  lstm_encoder_kernel<<<256, 512, 0, stream>>>(
      (const float*)d_in[0],
      (const float*)d_in[1], (const float*)d_in[2],
      (const float*)d_in[3], (const float*)d_in[4],
      (const float*)d_in[5], (const float*)d_in[6],
      (const float*)d_in[7], (const float*)d_in[8],
      (const float*)d_in[9], (const float*)d_in[10],
      (const float*)d_in[11], (const float*)d_in[12],
      (float*)d_out, flags, done, hf, hb, ce);
}